// Round 11
// baseline (734.119 us; speedup 1.0000x reference)
//
#include <hip/hip_runtime.h>

// GNNModel fused, R11 = R10 + sched_barrier(0) fences. R10 postmortem: spill
// traffic (853 MB) identical to R9 despite W moving to LDS -> the pre-RA
// scheduler hoists ALL 32 ds_read_b128 + biases per layer (~160 dwords) on
// top of h/hn (64) -> ~270-dword pressure vs 170-unified cap -> spills.
// Fix: __builtin_amdgcn_sched_barrier(0) after each nt/mt iteration bounds
// the scheduling window to ~24 in-flight dwords. Live set ~110 -> fits.
// Math identical to R10 (passed, absmax 3.05e-5).

typedef _Float16 half4v __attribute__((ext_vector_type(4)));
typedef _Float16 half8v __attribute__((ext_vector_type(8)));
typedef float    float4v __attribute__((ext_vector_type(4)));

constexpr int PP = 12, DIN = 32, H = 128, HO = 64, DOUT = 3, NL = 3;
// ws layout (halves):
//   wsP [mt=8][lane=64][8]  : Win^T A-frags (j<4: kt=0, j>=4: kt=1)
//   wsG [l=3][nt=8][ktp=4][lane=64][8] : W B-frags (j<4: kt=2ktp, j>=4: 2ktp+1)
//   wsH1 [o=64][k=128]      : W_out1^T rows
constexpr int WSP_OFF = 0, WSG_OFF = 4096, WSH_OFF = 53248, WS_TOT = 61440;

__global__ __launch_bounds__(256)
void prep_weights(const float* __restrict__ W_in, const float* __restrict__ W_gcn,
                  const float* __restrict__ W_out1, _Float16* __restrict__ ws)
{
    int e = blockIdx.x * 256 + threadIdx.x;
    if (e < WSG_OFF) {                         // wsP
        int mt = e >> 9, lane = (e >> 3) & 63, hh = e & 7;
        int q = lane >> 4, qm = lane & 15;
        int din = 16 * (hh >> 2) + 4 * q + (hh & 3);
        ws[e] = (_Float16)W_in[din * H + 16 * mt + qm];
    } else if (e < WSH_OFF) {                  // wsG
        int e2 = e - WSG_OFF;
        int l = e2 >> 14, r = e2 & 16383;
        int nt = r >> 11, ktp = (r >> 9) & 3, lane = (r >> 3) & 63, hh = r & 7;
        int q = lane >> 4, qm = lane & 15;
        int hi = 32 * ktp + 16 * (hh >> 2) + 4 * q + (hh & 3);
        ws[e] = (_Float16)W_gcn[l * (H * H) + hi * H + 16 * nt + qm];
    } else if (e < WS_TOT) {                   // wsH1
        int e3 = e - WSH_OFF;
        int o = e3 >> 7, k = e3 & 127;
        ws[e] = (_Float16)W_out1[k * HO + o];
    }
}

__device__ inline half4v lo4(half8v v) { return __builtin_shufflevector(v, v, 0, 1, 2, 3); }
__device__ inline half4v hi4(half8v v) { return __builtin_shufflevector(v, v, 4, 5, 6, 7); }
__device__ inline half4v pk4(float a, float b, float c, float d) {
    half4v r; r[0] = (_Float16)a; r[1] = (_Float16)b; r[2] = (_Float16)c; r[3] = (_Float16)d;
    return r;
}

__global__ __launch_bounds__(256, 3)
void gnn_mfma(const float* __restrict__ x,
              const float* __restrict__ b_in,
              const float* __restrict__ b_gcn,
              const float* __restrict__ b_out1,
              const float* __restrict__ W_out2,
              const float* __restrict__ b_out2,
              const _Float16* __restrict__ ws,
              float* __restrict__ out)
{
    __shared__ _Float16 wbuf[H * H];           // 32 KB: one layer's W frags; tail h-dump alias
    __shared__ float    g_s[4][2][H];          // 4 KB

    const int tid = threadIdx.x, lane = tid & 63, wave = tid >> 6;
    const int q = lane >> 4, qm = lane & 15;
    const int bb = blockIdx.x * 8 + wave * 2;  // this wave's 2 batches
    const int pcl = (qm < PP) ? qm : (PP - 1); // planet clamp (rows 12..15 dup 11)

    // ---- stage layer-0 W into LDS ----
    #pragma unroll
    for (int i = 0; i < 8; ++i)
        *(half8v*)&wbuf[i * 2048 + tid * 8] =
            *(const half8v*)&ws[WSG_OFF + i * 2048 + tid * 8];
    __builtin_amdgcn_sched_barrier(0);

    // ---- adjacency B-frags af[b] (bit-exact fp32 mask; A=mask+eye, diag 2) ----
    float lon_own = x[((size_t)bb + (q & 1)) * (PP * DIN) + pcl * DIN];
    float deg = 1.0f;
    #pragma unroll
    for (int j = 0; j < PP; ++j) {
        float lj = __shfl(lon_own, ((q & 1) << 4) + j, 64);
        float d = fabsf(lon_own - lj);
        d = fminf(d, 360.0f - d);
        deg += (d < 10.0f) ? 1.0f : 0.0f;
    }
    float dinv_own = __frsqrt_rn(fmaxf(deg, 1e-12f));
    half4v af[2];
    #pragma unroll
    for (int b = 0; b < 2; ++b) {
        float lon_n = __shfl(lon_own, (b << 4) + qm, 64);
        float dv_n  = __shfl(dinv_own, (b << 4) + qm, 64);
        half4v a;
        #pragma unroll
        for (int j = 0; j < 4; ++j) {
            int p = 4 * q + j;
            float lon_k = __shfl(lon_own, (b << 4) + p, 64);
            float dv_k  = __shfl(dinv_own, (b << 4) + p, 64);
            float d = fabsf(lon_k - lon_n);
            d = fminf(d, 360.0f - d);
            float m = (d < 10.0f) ? 1.0f : 0.0f;
            if (p == qm) m += 1.0f;
            float v = (p < PP && qm < PP) ? m * dv_k * dv_n : 0.0f;
            a[j] = (_Float16)v;
        }
        af[b] = a;
    }
    __builtin_amdgcn_sched_barrier(0);

    // ---- proj: h0^T = Win^T @ X^T ----
    half4v h[2][8];
    {
        half4v bx[2][2];
        #pragma unroll
        for (int nt = 0; nt < 2; ++nt) {
            const float* xp = x + ((size_t)(bb + nt)) * (PP * DIN) + pcl * DIN;
            float4 v0 = *(const float4*)&xp[4 * q];
            float4 v1 = *(const float4*)&xp[16 + 4 * q];
            bx[nt][0] = pk4(v0.x, v0.y, v0.z, v0.w);
            bx[nt][1] = pk4(v1.x, v1.y, v1.z, v1.w);
        }
        __builtin_amdgcn_sched_barrier(0);
        #pragma unroll
        for (int mt = 0; mt < 8; ++mt) {
            half8v wa = *(const half8v*)&ws[WSP_OFF + (mt * 64 + lane) * 8];
            float4 bi = *(const float4*)&b_in[16 * mt + 4 * q];
            #pragma unroll
            for (int nt = 0; nt < 2; ++nt) {
                float4v c = {0.f, 0.f, 0.f, 0.f};
                c = __builtin_amdgcn_mfma_f32_16x16x16f16(lo4(wa), bx[nt][0], c, 0, 0, 0);
                c = __builtin_amdgcn_mfma_f32_16x16x16f16(hi4(wa), bx[nt][1], c, 0, 0, 0);
                h[nt][mt] = pk4(c[0] + bi.x, c[1] + bi.y, c[2] + bi.z, c[3] + bi.w);
            }
            __builtin_amdgcn_sched_barrier(0);
        }
    }
    __syncthreads();   // B1: wbuf(layer 0) staged

    // ---- GCN layers: W B-frags from LDS; sched fence per nt ----
    #pragma unroll
    for (int l = 0; l < NL; ++l) {
        half4v hn[2][8];
        #pragma unroll
        for (int nt = 0; nt < 8; ++nt) {
            float4v a0 = {0.f, 0.f, 0.f, 0.f}, a1 = {0.f, 0.f, 0.f, 0.f};
            #pragma unroll
            for (int ktp = 0; ktp < 4; ++ktp) {
                half8v w8 = *(const half8v*)&wbuf[(nt * 4 + ktp) * 512 + lane * 8];
                a0 = __builtin_amdgcn_mfma_f32_16x16x16f16(h[0][2 * ktp],     lo4(w8), a0, 0, 0, 0);
                a1 = __builtin_amdgcn_mfma_f32_16x16x16f16(h[1][2 * ktp],     lo4(w8), a1, 0, 0, 0);
                a0 = __builtin_amdgcn_mfma_f32_16x16x16f16(h[0][2 * ktp + 1], hi4(w8), a0, 0, 0, 0);
                a1 = __builtin_amdgcn_mfma_f32_16x16x16f16(h[1][2 * ktp + 1], hi4(w8), a1, 0, 0, 0);
            }
            float4 bg = *(const float4*)&b_gcn[l * H + 16 * nt + 4 * q];
            #pragma unroll
            for (int b = 0; b < 2; ++b) {
                float4v t = b ? a1 : a0;
                half4v tp = pk4(t[0], t[1], t[2], t[3]);     // t C-tile -> mix A-frag (t^T)
                float4v d = {0.f, 0.f, 0.f, 0.f};
                d = __builtin_amdgcn_mfma_f32_16x16x16f16(tp, af[b], d, 0, 0, 0);
                hn[b][nt] = pk4(fmaxf(d[0] + bg.x, 0.f), fmaxf(d[1] + bg.y, 0.f),
                                fmaxf(d[2] + bg.z, 0.f), fmaxf(d[3] + bg.w, 0.f));
            }
            __builtin_amdgcn_sched_barrier(0);
        }
        #pragma unroll
        for (int b = 0; b < 2; ++b)
            #pragma unroll
            for (int nt = 0; nt < 8; ++nt)
                h[b][nt] = hn[b][nt];

        __syncthreads();                       // WAR: all waves done reading wbuf
        if (l + 1 < NL) {
            #pragma unroll
            for (int i = 0; i < 8; ++i)
                *(half8v*)&wbuf[i * 2048 + tid * 8] =
                    *(const half8v*)&ws[WSG_OFF + (l + 1) * 16384 + i * 2048 + tid * 8];
            __builtin_amdgcn_sched_barrier(0);
            __syncthreads();                   // RAW: next layer's wbuf ready
        }
    }

    // ---- tail: wbuf dead (post-WAR barrier) -> wave-private h dump ----
    _Float16 (*h3s)[2][PP][136] = (_Float16 (*)[2][PP][136])wbuf;   // 25.5 KB <= 32 KB
    #pragma unroll
    for (int b = 0; b < 2; ++b)
        #pragma unroll
        for (int nt = 0; nt < 8; ++nt)
            if (qm < PP)
                *(half4v*)&h3s[wave][b][qm][16 * nt + 4 * q] = h[b][nt];

    float o1[2];
    #pragma unroll
    for (int b = 0; b < 2; ++b) {
        float s0 = 0.f, s1 = 0.f;
        #pragma unroll
        for (int p = 0; p < PP; ++p) {
            s0 += (float)h3s[wave][b][p][lane];
            s1 += (float)h3s[wave][b][p][lane + 64];
        }
        g_s[wave][b][lane]      = s0 * (1.0f / 12.0f);
        g_s[wave][b][lane + 64] = s1 * (1.0f / 12.0f);
    }
    #pragma unroll
    for (int b = 0; b < 2; ++b) {
        float acc = b_out1[lane];
        const _Float16* wr = ws + WSH_OFF + lane * H;
        #pragma unroll
        for (int kk = 0; kk < H / 8; ++kk) {
            half8v wv = *(const half8v*)&wr[8 * kk];
            #pragma unroll
            for (int j = 0; j < 8; ++j) acc += g_s[wave][b][8 * kk + j] * (float)wv[j];
        }
        o1[b] = fmaxf(acc, 0.f);
    }
    float w20 = W_out2[lane * DOUT + 0];
    float w21 = W_out2[lane * DOUT + 1];
    float w22 = W_out2[lane * DOUT + 2];
    #pragma unroll
    for (int b = 0; b < 2; ++b) {
        float p0 = o1[b] * w20, p1 = o1[b] * w21, p2 = o1[b] * w22;
        #pragma unroll
        for (int off = 32; off > 0; off >>= 1) {
            p0 += __shfl_down(p0, off, 64);
            p1 += __shfl_down(p1, off, 64);
            p2 += __shfl_down(p2, off, 64);
        }
        if (lane == 0) {
            float* o = out + (size_t)(bb + b) * DOUT;
            o[0] = p0 + b_out2[0];
            o[1] = p1 + b_out2[1];
            o[2] = p2 + b_out2[2];
        }
    }
}

extern "C" void kernel_launch(void* const* d_in, const int* in_sizes, int n_in,
                              void* d_out, int out_size, void* d_ws, size_t ws_size,
                              hipStream_t stream) {
    const float* x      = (const float*)d_in[0];
    const float* W_in   = (const float*)d_in[1];
    const float* b_in   = (const float*)d_in[2];
    const float* W_gcn  = (const float*)d_in[3];
    const float* b_gcn  = (const float*)d_in[4];
    const float* W_out1 = (const float*)d_in[5];
    const float* b_out1 = (const float*)d_in[6];
    const float* W_out2 = (const float*)d_in[7];
    const float* b_out2 = (const float*)d_in[8];
    float* outp         = (float*)d_out;
    _Float16* wsh       = (_Float16*)d_ws;

    const int B = in_sizes[0] / (PP * DIN);    // 65536

    hipLaunchKernelGGL(prep_weights, dim3((WS_TOT + 255) / 256), dim3(256), 0, stream,
                       W_in, W_gcn, W_out1, wsh);
    hipLaunchKernelGGL(gnn_mfma, dim3(B / 8), dim3(256), 0, stream,
                       x, b_in, b_gcn, b_out1, W_out2, b_out2, wsh, outp);
}

// Round 12
// 480.534 us; speedup vs baseline: 1.5277x; 1.5277x over previous
//
#include <hip/hip_runtime.h>

// GNNModel fused via MFMA. R12 = R7 (lean registers, proven spill-free)
// + K=16 C->A chaining for the mix (validated in R8-R11): t C-tiles feed
// the mix MFMA directly as A-frags (16x16x16: C/D layout == A/B layout),
// so the tT transpose array, its LDS round-trip and one serialization hop
// per layer are deleted. Amat B-frags (9 x b64) re-read from LDS per layer
// (nothing big lives across barriers -> no spill). LDS 37.5 -> 19.5 KB.
// Adjacency bit-exact fp32; A = mask + eye (diag 2).

typedef _Float16 half4v __attribute__((ext_vector_type(4)));
typedef _Float16 half8v __attribute__((ext_vector_type(8)));
typedef float    float4v __attribute__((ext_vector_type(4)));

constexpr int PP = 12, DIN = 32, H = 128, HO = 64, DOUT = 3, NL = 3;
constexpr int NB = 4, ROWS = NB * PP;   // 48 rows per block (4 batches x 12)
constexpr int HP  = 136;                // h_a stride (halves)
constexpr int AP2 = 72;                 // AmatT stride (halves)

// ws layout in halves: WinT[128][32] @0 ; WgT[3][128][128] @4096 ; W1T[64][128] @53248
constexpr int WS_WG = 4096, WS_W1 = 53248, WS_TOT = 61440;

__global__ __launch_bounds__(256)
void prep_weights(const float* __restrict__ W_in, const float* __restrict__ W_gcn,
                  const float* __restrict__ W_out1, _Float16* __restrict__ ws)
{
    int e = blockIdx.x * 256 + threadIdx.x;
    if (e < WS_WG) {                        // WinT[n][k] = W_in[k][n]
        int n = e >> 5, k = e & 31;
        ws[e] = (_Float16)W_in[k * H + n];
    } else if (e < WS_W1) {                 // WgT[l][n][k] = W_gcn[l][k][n]
        int e2 = e - WS_WG;
        int l = e2 >> 14, r = e2 & 16383, n = r >> 7, k = r & 127;
        ws[e] = (_Float16)W_gcn[l * (H * H) + k * H + n];
    } else if (e < WS_TOT) {                // W1T[o][k] = W_out1[k][o]
        int e3 = e - WS_W1;
        int o = e3 >> 7, k = e3 & 127;
        ws[e] = (_Float16)W_out1[k * HO + o];
    }
}

__device__ inline half4v pk4(float a, float b, float c, float d) {
    half4v r; r[0] = (_Float16)a; r[1] = (_Float16)b; r[2] = (_Float16)c; r[3] = (_Float16)d;
    return r;
}

__global__ __launch_bounds__(256, 4)
void gnn_mfma(const float* __restrict__ x,
              const float* __restrict__ b_in,
              const float* __restrict__ b_gcn,
              const float* __restrict__ b_out1,
              const float* __restrict__ W_out2,
              const float* __restrict__ b_out2,
              const _Float16* __restrict__ ws,
              float* __restrict__ out)
{
    __shared__ _Float16 h_a[ROWS][HP];                 // 12.75 KB
    __shared__ __align__(16) char r3[ROWS * AP2 * 2];  // 6.75 KB: AmatT, later g_s
    _Float16 (*AmatT)[AP2] = (_Float16 (*)[AP2])r3;
    float (*g_s)[H] = (float (*)[H])r3;                // [4][128] fp32 (2 KB)

    const int tid  = threadIdx.x;
    const int lane = tid & 63, wave = tid >> 6;
    const int q = lane >> 4, qm = lane & 15;
    const int b0 = blockIdx.x * NB;
    const float* xblk = x + (size_t)b0 * (PP * DIN);

    // ---- issue x loads (lon + proj B-frag quads) ----
    float lon_own = 0.f;
    if (lane < PP) lon_own = xblk[(wave * PP + lane) * DIN];
    float4 xa[3], xb[3];
    #pragma unroll
    for (int nt = 0; nt < 3; ++nt) {
        const float* p = xblk + (16 * nt + qm) * DIN + 8 * q;
        xa[nt] = *(const float4*)p;
        xb[nt] = *(const float4*)(p + 4);
    }

    // ---- adjacency via shfl (bit-exact fp32 mask); wave w = batch w ----
    {
        float lonj[PP];
        #pragma unroll
        for (int j = 0; j < PP; ++j) lonj[j] = __shfl(lon_own, j, 64);
        float deg = 1.0f;                              // GCNConv's appended self-loop
        #pragma unroll
        for (int j = 0; j < PP; ++j) {
            float d = fabsf(lon_own - lonj[j]);
            d = fminf(d, 360.0f - d);
            deg += (d < 10.0f) ? 1.0f : 0.0f;          // diag: d=0 -> 1
        }
        float dinv_own = rsqrtf(fmaxf(deg, 1e-12f));
        float dj[PP];
        #pragma unroll
        for (int j = 0; j < PP; ++j) dj[j] = __shfl(dinv_own, j, 64);

        if (lane < PP) {
            const int n = wave * PP + lane;
            half8v z = {0, 0, 0, 0, 0, 0, 0, 0};
            #pragma unroll
            for (int c = 0; c < 48; c += 8) *(half8v*)&AmatT[n][c] = z;
            _Float16 vals[PP];
            #pragma unroll
            for (int j = 0; j < PP; ++j) {
                float d = fabsf(lon_own - lonj[j]);
                d = fminf(d, 360.0f - d);
                float a = (d < 10.0f) ? 1.0f : 0.0f;
                if (j == lane) a += 1.0f;              // A = mask + eye: diag = 2
                vals[j] = (_Float16)(a * dinv_own * dj[j]);
            }
            #pragma unroll
            for (int t4 = 0; t4 < 3; ++t4) {
                half4v v;
                v[0] = vals[4 * t4]; v[1] = vals[4 * t4 + 1];
                v[2] = vals[4 * t4 + 2]; v[3] = vals[4 * t4 + 3];
                *(half4v*)&AmatT[n][wave * PP + 4 * t4] = v;
            }
        }
    }

    // ---- proj: h0^T = WinT @ x^T -> h_a[planet row][wave-own cols] ----
    {
        half8v bx[3];
        #pragma unroll
        for (int nt = 0; nt < 3; ++nt) {
            half8v h;
            h[0] = (_Float16)xa[nt].x; h[1] = (_Float16)xa[nt].y;
            h[2] = (_Float16)xa[nt].z; h[3] = (_Float16)xa[nt].w;
            h[4] = (_Float16)xb[nt].x; h[5] = (_Float16)xb[nt].y;
            h[6] = (_Float16)xb[nt].z; h[7] = (_Float16)xb[nt].w;
            bx[nt] = h;
        }
        #pragma unroll
        for (int mt2 = 0; mt2 < 2; ++mt2) {
            const int m = 32 * wave + 16 * mt2;
            half8v aw = *(const half8v*)&ws[(m + qm) * DIN + 8 * q];
            float4 bi = *(const float4*)&b_in[m + 4 * q];
            #pragma unroll
            for (int nt = 0; nt < 3; ++nt) {
                float4v c = {0.f, 0.f, 0.f, 0.f};
                c = __builtin_amdgcn_mfma_f32_16x16x32_f16(aw, bx[nt], c, 0, 0, 0);
                *(half4v*)&h_a[16 * nt + qm][m + 4 * q] =
                    pk4(c[0] + bi.x, c[1] + bi.y, c[2] + bi.z, c[3] + bi.w);
            }
        }
    }
    __syncthreads();   // B1: h_a + AmatT complete

    const _Float16* WgT = ws + WS_WG;

    // ---- GCN layers ----
    #pragma unroll
    for (int l = 0; l < NL; ++l) {
        // W B-frags for this phase only (consumed before the barrier)
        const _Float16* Wl = WgT + l * (H * H);
        half8v bw[2][4];
        #pragma unroll
        for (int n2 = 0; n2 < 2; ++n2)
            #pragma unroll
            for (int kt = 0; kt < 4; ++kt)
                bw[n2][kt] = *(const half8v*)&Wl[(32 * wave + 16 * n2 + qm) * H + 32 * kt + 8 * q];

        // t = h @ Wl  (K=32 MFMA; A-frags from h_a)
        float4v c[3][2];
        #pragma unroll
        for (int mt = 0; mt < 3; ++mt) {
            c[mt][0] = (float4v){0.f, 0.f, 0.f, 0.f};
            c[mt][1] = (float4v){0.f, 0.f, 0.f, 0.f};
        }
        #pragma unroll
        for (int kt = 0; kt < 4; ++kt)
            #pragma unroll
            for (int mt = 0; mt < 3; ++mt) {
                half8v a = *(const half8v*)&h_a[16 * mt + qm][32 * kt + 8 * q];
                c[mt][0] = __builtin_amdgcn_mfma_f32_16x16x32_f16(a, bw[0][kt], c[mt][0], 0, 0, 0);
                c[mt][1] = __builtin_amdgcn_mfma_f32_16x16x32_f16(a, bw[1][kt], c[mt][1], 0, 0, 0);
            }

        // pack t C-tiles -> mix A-frags (t^T), in-register (chaining identity)
        half4v ah[3][2];
        #pragma unroll
        for (int mt = 0; mt < 3; ++mt)
            #pragma unroll
            for (int n2 = 0; n2 < 2; ++n2)
                ah[mt][n2] = pk4(c[mt][n2][0], c[mt][n2][1], c[mt][n2][2], c[mt][n2][3]);

        __syncthreads();   // B2: all waves done reading h_a (WAR vs mix writes)

        // mix: h'^T = t^T @ Amat (Ahat symmetric); Amat B-frags from LDS (b64)
        half4v bA[3][3];   // [kt][nt]
        #pragma unroll
        for (int kt = 0; kt < 3; ++kt)
            #pragma unroll
            for (int nt = 0; nt < 3; ++nt)
                bA[kt][nt] = *(const half4v*)&AmatT[16 * nt + qm][16 * kt + 4 * q];

        #pragma unroll
        for (int n2 = 0; n2 < 2; ++n2) {
            float4 bg = *(const float4*)&b_gcn[l * H + 32 * wave + 16 * n2 + 4 * q];
            #pragma unroll
            for (int nt = 0; nt < 3; ++nt) {
                float4v d = {0.f, 0.f, 0.f, 0.f};
                d = __builtin_amdgcn_mfma_f32_16x16x16f16(ah[0][n2], bA[0][nt], d, 0, 0, 0);
                d = __builtin_amdgcn_mfma_f32_16x16x16f16(ah[1][n2], bA[1][nt], d, 0, 0, 0);
                d = __builtin_amdgcn_mfma_f32_16x16x16f16(ah[2][n2], bA[2][nt], d, 0, 0, 0);
                *(half4v*)&h_a[16 * nt + qm][32 * wave + 16 * n2 + 4 * q] =
                    pk4(fmaxf(d[0] + bg.x, 0.f), fmaxf(d[1] + bg.y, 0.f),
                        fmaxf(d[2] + bg.z, 0.f), fmaxf(d[3] + bg.w, 0.f));
            }
        }
        __syncthreads();   // B3: RAW for next layer / pool (pool reads all cols)
    }

    // ---- tail: wave w owns batch w ----
    {
        float s0 = 0.f, s1 = 0.f;
        #pragma unroll
        for (int p = 0; p < PP; ++p) {
            s0 += (float)h_a[wave * PP + p][lane];
            s1 += (float)h_a[wave * PP + p][lane + 64];
        }
        // r3 alias: AmatT dead (last bA read was pre-B3 of layer 2)
        g_s[wave][lane]      = s0 * (1.0f / 12.0f);
        g_s[wave][lane + 64] = s1 * (1.0f / 12.0f);
    }
    float o1;
    {
        float acc = b_out1[lane];
        const _Float16* wr = ws + WS_W1 + lane * H;
        #pragma unroll
        for (int kk = 0; kk < H / 8; ++kk) {
            half8v wv = *(const half8v*)&wr[8 * kk];
            #pragma unroll
            for (int j = 0; j < 8; ++j) acc += g_s[wave][8 * kk + j] * (float)wv[j];
        }
        o1 = fmaxf(acc, 0.f);
    }
    {
        float p0 = o1 * W_out2[lane * DOUT + 0];
        float p1 = o1 * W_out2[lane * DOUT + 1];
        float p2 = o1 * W_out2[lane * DOUT + 2];
        #pragma unroll
        for (int off = 32; off > 0; off >>= 1) {
            p0 += __shfl_down(p0, off, 64);
            p1 += __shfl_down(p1, off, 64);
            p2 += __shfl_down(p2, off, 64);
        }
        if (lane == 0) {
            float* o = out + (size_t)(b0 + wave) * DOUT;
            o[0] = p0 + b_out2[0];
            o[1] = p1 + b_out2[1];
            o[2] = p2 + b_out2[2];
        }
    }
}

extern "C" void kernel_launch(void* const* d_in, const int* in_sizes, int n_in,
                              void* d_out, int out_size, void* d_ws, size_t ws_size,
                              hipStream_t stream) {
    const float* x      = (const float*)d_in[0];
    const float* W_in   = (const float*)d_in[1];
    const float* b_in   = (const float*)d_in[2];
    const float* W_gcn  = (const float*)d_in[3];
    const float* b_gcn  = (const float*)d_in[4];
    const float* W_out1 = (const float*)d_in[5];
    const float* b_out1 = (const float*)d_in[6];
    const float* W_out2 = (const float*)d_in[7];
    const float* b_out2 = (const float*)d_in[8];
    float* outp         = (float*)d_out;
    _Float16* wsh       = (_Float16*)d_ws;

    const int B = in_sizes[0] / (PP * DIN);        // 65536

    hipLaunchKernelGGL(prep_weights, dim3((WS_TOT + 255) / 256), dim3(256), 0, stream,
                       W_in, W_gcn, W_out1, wsh);
    hipLaunchKernelGGL(gnn_mfma, dim3(B / NB), dim3(256), 0, stream,
                       x, b_in, b_gcn, b_out1, W_out2, b_out2, wsh, outp);
}